// Round 1
// baseline (1406.771 us; speedup 1.0000x reference)
//
#include <hip/hip_runtime.h>
#include <cstdint>
#include <cstddef>

#define VOCAB 32000
#define EMB 512
#define HID 1024
#define SEQ 512
#define BATCH 128
#define SPLIT 8   // s-dimension splits per batch element in attention pass

__device__ __forceinline__ float sigmoidf_(float x) { return 1.f / (1.f + __expf(-x)); }

// ---------------------------------------------------------------------------
// init: predictions[b,v] = b_fc[v]; gates[b,r] = b_ih[r] + b_hh[r]
// (GEMMs accumulate into these with atomicAdd)
// ---------------------------------------------------------------------------
__global__ void init_kernel(float* __restrict__ pred, float* __restrict__ gates,
                            const float* __restrict__ b_fc, const float* __restrict__ b_ih,
                            const float* __restrict__ b_hh)
{
    const int i = blockIdx.x * 256 + threadIdx.x;
    const int npred = BATCH * VOCAB;
    if (i < npred) {
        pred[i] = b_fc[i % VOCAB];
    } else {
        const int j = i - npred;
        if (j < BATCH * 4 * HID) {
            const int r = j & (4 * HID - 1);
            gates[j] = b_ih[r] + b_hh[r];
        }
    }
}

// ---------------------------------------------------------------------------
// Fused attention: single pass over encoder_states.
// Block = (b, chunk of 64 s-values). 4 waves, each wave owns 16 s-values.
// Per s: load enc[s,b,0:2048] (32 floats/lane), dot with W_e[1024:3072]
// (kept in registers), wave-reduce, e = relu(dot + hdot), p = exp(e),
// accumulate p*enc into 32 register accumulators + p into lsum.
// relu >= 0 and |energy| small => exp without max-subtraction is safe.
// ---------------------------------------------------------------------------
__global__ __launch_bounds__(256, 4) void attn_partial_kernel(
    const float* __restrict__ enc, const float* __restrict__ hidden,
    const float* __restrict__ W_e, const float* __restrict__ b_e,
    float* __restrict__ ctxPartial, float* __restrict__ lPartial)
{
    const int blk  = blockIdx.x;
    const int b    = blk >> 3;     // blk / SPLIT
    const int chnk = blk & 7;      // blk % SPLIT
    const int t    = threadIdx.x;
    const int wave = t >> 6;
    const int lane = t & 63;

    __shared__ float red[4];
    __shared__ float l_sh[4];
    __shared__ float ctx_sh[4][2048];

    // hdot = dot(hidden[b,:], W_e[0:1024]) + b_e   (block-wide reduction)
    float4 hv = *(const float4*)&hidden[(size_t)b * HID + t * 4];
    float4 wv = *(const float4*)&W_e[t * 4];
    float hl = hv.x * wv.x + hv.y * wv.y + hv.z * wv.z + hv.w * wv.w;
    #pragma unroll
    for (int off = 32; off > 0; off >>= 1) hl += __shfl_down(hl, off, 64);
    if (lane == 0) red[wave] = hl;
    __syncthreads();
    const float hdot = red[0] + red[1] + red[2] + red[3] + b_e[0];

    // encoder weight fragment, kept in registers for the whole loop
    float4 w[8];
    #pragma unroll
    for (int j = 0; j < 8; j++)
        w[j] = *(const float4*)&W_e[HID + j * 256 + lane * 4];

    float4 c[8];
    #pragma unroll
    for (int j = 0; j < 8; j++) c[j] = make_float4(0.f, 0.f, 0.f, 0.f);
    float lsum = 0.f;

    #pragma unroll 1
    for (int i = 0; i < 16; i++) {
        const int s = chnk * 64 + wave + i * 4;
        const float* p = enc + ((size_t)s * BATCH + b) * 2048;
        float4 e[8];
        #pragma unroll
        for (int j = 0; j < 8; j++)
            e[j] = *(const float4*)&p[j * 256 + lane * 4];
        float d = 0.f;
        #pragma unroll
        for (int j = 0; j < 8; j++)
            d += e[j].x * w[j].x + e[j].y * w[j].y + e[j].z * w[j].z + e[j].w * w[j].w;
        #pragma unroll
        for (int off = 32; off > 0; off >>= 1) d += __shfl_xor(d, off, 64);
        float energy = d + hdot;
        energy = energy > 0.f ? energy : 0.f;
        const float pr = __expf(energy);
        lsum += pr;
        #pragma unroll
        for (int j = 0; j < 8; j++) {
            c[j].x += pr * e[j].x; c[j].y += pr * e[j].y;
            c[j].z += pr * e[j].z; c[j].w += pr * e[j].w;
        }
    }

    // combine 4 waves within the block via LDS
    #pragma unroll
    for (int j = 0; j < 8; j++)
        *(float4*)&ctx_sh[wave][j * 256 + lane * 4] = c[j];
    if (lane == 0) l_sh[wave] = lsum;
    __syncthreads();

    float* outp = ctxPartial + (size_t)blk * 2048;
    #pragma unroll
    for (int j = 0; j < 8; j++) {
        const int idx = j * 256 + t;
        outp[idx] = ctx_sh[0][idx] + ctx_sh[1][idx] + ctx_sh[2][idx] + ctx_sh[3][idx];
    }
    if (t == 0) lPartial[blk] = l_sh[0] + l_sh[1] + l_sh[2] + l_sh[3];
}

// ---------------------------------------------------------------------------
// Combine SPLIT partials -> normalized context; append embedding gather.
// rnn_in[b, 0:2048] = context[b], rnn_in[b, 2048:2560] = emb_table[x[b]]
// ---------------------------------------------------------------------------
__global__ void combine_kernel(const float* __restrict__ ctxPartial,
                               const float* __restrict__ lPartial,
                               const int* __restrict__ x,
                               const float* __restrict__ emb_table,
                               float* __restrict__ rnn_in)
{
    const int b = blockIdx.x;
    const int t = threadIdx.x;
    float L = 0.f;
    #pragma unroll
    for (int cN = 0; cN < SPLIT; cN++) L += lPartial[b * SPLIT + cN];
    const float inv = 1.f / L;
    float* out = rnn_in + (size_t)b * 2560;
    #pragma unroll
    for (int j = 0; j < 8; j++) {
        const int h = j * 256 + t;
        float v = 0.f;
        #pragma unroll
        for (int cN = 0; cN < SPLIT; cN++)
            v += ctxPartial[((size_t)(b * SPLIT + cN)) * 2048 + h];
        out[h] = v * inv;
    }
    const int tok = x[b];
    for (int e2 = t; e2 < EMB; e2 += 256)
        out[2048 + e2] = emb_table[(size_t)tok * EMB + e2];
}

// ---------------------------------------------------------------------------
// fp32 GEMM: C[128, N] += X[128, K-slice] @ W[N, K-slice]^T   (atomicAdd)
// Tile: 128 n x 128 b, BK=16 K-panel. 256 threads, each 8x8 outputs.
// blockIdx.x = n-tile, blockIdx.y = k-split (kChunk columns each).
// ---------------------------------------------------------------------------
__global__ __launch_bounds__(256, 2) void gemm_xt_atomic(
    float* __restrict__ C, const float* __restrict__ X, const float* __restrict__ W,
    int N, int K, int kChunk)
{
    __shared__ float Ws[16][132];
    __shared__ float Xs[16][132];
    const int t  = threadIdx.x;
    const int tx = t & 15;    // n-group (8 rows of W)
    const int ty = t >> 4;    // b-group (8 batch)
    const int nBase = blockIdx.x * 128;
    const int k0   = blockIdx.y * kChunk;
    const int kEnd = k0 + kChunk;

    float acc[8][8];
    #pragma unroll
    for (int i = 0; i < 8; i++)
        #pragma unroll
        for (int j = 0; j < 8; j++) acc[i][j] = 0.f;

    const int rl = t >> 2;          // 0..63
    const int kq = (t & 3) * 4;     // 0,4,8,12

    for (int kk = k0; kk < kEnd; kk += 16) {
        __syncthreads();
        float4 w0 = *(const float4*)&W[(size_t)(nBase + rl) * K + kk + kq];
        float4 w1 = *(const float4*)&W[(size_t)(nBase + rl + 64) * K + kk + kq];
        float4 x0 = *(const float4*)&X[(size_t)rl * K + kk + kq];
        float4 x1 = *(const float4*)&X[(size_t)(rl + 64) * K + kk + kq];
        Ws[kq + 0][rl] = w0.x; Ws[kq + 1][rl] = w0.y; Ws[kq + 2][rl] = w0.z; Ws[kq + 3][rl] = w0.w;
        Ws[kq + 0][rl + 64] = w1.x; Ws[kq + 1][rl + 64] = w1.y; Ws[kq + 2][rl + 64] = w1.z; Ws[kq + 3][rl + 64] = w1.w;
        Xs[kq + 0][rl] = x0.x; Xs[kq + 1][rl] = x0.y; Xs[kq + 2][rl] = x0.z; Xs[kq + 3][rl] = x0.w;
        Xs[kq + 0][rl + 64] = x1.x; Xs[kq + 1][rl + 64] = x1.y; Xs[kq + 2][rl + 64] = x1.z; Xs[kq + 3][rl + 64] = x1.w;
        __syncthreads();
        #pragma unroll
        for (int k = 0; k < 16; k++) {
            float4 wa = *(const float4*)&Ws[k][tx * 8];
            float4 wb = *(const float4*)&Ws[k][tx * 8 + 4];
            float4 xa = *(const float4*)&Xs[k][ty * 8];
            float4 xb = *(const float4*)&Xs[k][ty * 8 + 4];
            float w8[8] = {wa.x, wa.y, wa.z, wa.w, wb.x, wb.y, wb.z, wb.w};
            float x8[8] = {xa.x, xa.y, xa.z, xa.w, xb.x, xb.y, xb.z, xb.w};
            #pragma unroll
            for (int i = 0; i < 8; i++)
                #pragma unroll
                for (int j = 0; j < 8; j++)
                    acc[i][j] += x8[i] * w8[j];
        }
    }

    #pragma unroll
    for (int i = 0; i < 8; i++) {
        const int b = ty * 8 + i;
        float* row = C + (size_t)b * N + nBase + tx * 8;
        #pragma unroll
        for (int j = 0; j < 8; j++)
            atomicAdd(&row[j], acc[i][j]);
    }
}

// ---------------------------------------------------------------------------
// LSTM pointwise. gates[b, 0:4H] in torch order i,f,g,o.
// ---------------------------------------------------------------------------
__global__ void lstm_kernel(const float* __restrict__ gates, const float* __restrict__ cell,
                            float* __restrict__ h_out, float* __restrict__ c_out)
{
    const int idx = blockIdx.x * 256 + threadIdx.x;   // < 131072
    const int b = idx >> 10;
    const int h = idx & 1023;
    const float* g = gates + (size_t)b * (4 * HID);
    const float ig = sigmoidf_(g[h]);
    const float fg = sigmoidf_(g[HID + h]);
    const float gg = tanhf(g[2 * HID + h]);
    const float og = sigmoidf_(g[3 * HID + h]);
    const float cn = fg * cell[idx] + ig * gg;
    c_out[idx] = cn;
    h_out[idx] = og * tanhf(cn);
}

// ---------------------------------------------------------------------------
extern "C" void kernel_launch(void* const* d_in, const int* in_sizes, int n_in,
                              void* d_out, int out_size, void* d_ws, size_t ws_size,
                              hipStream_t stream)
{
    const int*   x      = (const int*)  d_in[0];
    const float* enc    = (const float*)d_in[1];
    const float* hidden = (const float*)d_in[2];
    const float* cell   = (const float*)d_in[3];
    const float* emb    = (const float*)d_in[4];
    const float* W_e    = (const float*)d_in[5];
    const float* b_e    = (const float*)d_in[6];
    const float* W_ih   = (const float*)d_in[7];
    const float* W_hh   = (const float*)d_in[8];
    const float* b_ih   = (const float*)d_in[9];
    const float* b_hh   = (const float*)d_in[10];
    const float* W_fc   = (const float*)d_in[11];
    const float* b_fc   = (const float*)d_in[12];

    float* pred  = (float*)d_out;                       // [128, 32000]
    float* h_out = pred + (size_t)BATCH * VOCAB;        // [128, 1024]
    float* c_out = h_out + BATCH * HID;                 // [128, 1024]

    float* ws         = (float*)d_ws;
    float* ctxPartial = ws;                                        // 128*8*2048 = 2,097,152
    float* lPartial   = ctxPartial + (size_t)BATCH * SPLIT * 2048; // 1024
    float* rnn_in     = lPartial + BATCH * SPLIT;                  // 128*2560
    float* gates      = rnn_in + (size_t)BATCH * 2560;             // 128*4096

    // 1) bias-init the two atomic accumulators (pred, gates)
    init_kernel<<<18048, 256, 0, stream>>>(pred, gates, b_fc, b_ih, b_hh);
    // 2) fused attention (single pass over 512 MB encoder_states)
    attn_partial_kernel<<<BATCH * SPLIT, 256, 0, stream>>>(enc, hidden, W_e, b_e, ctxPartial, lPartial);
    // 3) softmax-normalize partials + embedding gather -> rnn_in
    combine_kernel<<<BATCH, 256, 0, stream>>>(ctxPartial, lPartial, x, emb, rnn_in);
    // 4) gates += rnn_in @ W_ih^T   (N=4096, K=2560, 8-way K-split -> 256 blocks)
    gemm_xt_atomic<<<dim3(32, 8), 256, 0, stream>>>(gates, rnn_in, W_ih, 4 * HID, 2 * HID + EMB, 320);
    // 5) gates += hidden @ W_hh^T   (N=4096, K=1024, 4-way K-split -> 128 blocks)
    gemm_xt_atomic<<<dim3(32, 4), 256, 0, stream>>>(gates, hidden, W_hh, 4 * HID, HID, 256);
    // 6) LSTM pointwise -> h_new, c_new
    lstm_kernel<<<(BATCH * HID) / 256, 256, 0, stream>>>(gates, cell, h_out, c_out);
    // 7) pred += h_new @ W_fc^T     (N=32000, K=1024, 2-way K-split -> 500 blocks)
    gemm_xt_atomic<<<dim3(VOCAB / 128, 2), 256, 0, stream>>>(pred, h_out, W_fc, VOCAB, HID, 512);
}

// Round 2
// 959.689 us; speedup vs baseline: 1.4659x; 1.4659x over previous
//
#include <hip/hip_runtime.h>
#include <cstdint>
#include <cstddef>

#define VOCAB 32000
#define EMB 512
#define HID 1024
#define SEQ 512
#define BATCH 128
#define SPLIT 8   // s-dimension splits per batch element in attention pass

typedef __bf16 bf16x8 __attribute__((ext_vector_type(8)));
typedef short  s16x8  __attribute__((ext_vector_type(8)));
typedef float  f32x4  __attribute__((ext_vector_type(4)));

__device__ __forceinline__ float sigmoidf_(float x) { return 1.f / (1.f + __expf(-x)); }

// fp32 -> bf16 (RNE), bit-level to avoid relying on __bf16 cast lowering
__device__ __forceinline__ unsigned short f2bu(float f) {
    union { float f; uint32_t u; } v; v.f = f;
    return (unsigned short)((v.u + 0x7FFFu + ((v.u >> 16) & 1u)) >> 16);
}

__device__ __forceinline__ bf16x8 cvt_bf8(float4 a, float4 b) {
    union { s16x8 s; bf16x8 b; } u;
    u.s[0] = (short)f2bu(a.x); u.s[1] = (short)f2bu(a.y);
    u.s[2] = (short)f2bu(a.z); u.s[3] = (short)f2bu(a.w);
    u.s[4] = (short)f2bu(b.x); u.s[5] = (short)f2bu(b.y);
    u.s[6] = (short)f2bu(b.z); u.s[7] = (short)f2bu(b.w);
    return u.b;
}

__device__ __forceinline__ bf16x8 load_bf8(const unsigned short* p) {
    union { s16x8 s; bf16x8 b; } u;
    u.s = *(const s16x8*)p;
    return u.b;
}

// ---------------------------------------------------------------------------
// init: gates[b,r] = b_ih[r] + b_hh[r] (atomic accumulator base);
//       hid_bf = bf16(hidden)  (A-operand for the W_hh part of gates GEMM)
// ---------------------------------------------------------------------------
__global__ void init_k(float* __restrict__ gates, unsigned short* __restrict__ hid_bf,
                       const float* __restrict__ b_ih, const float* __restrict__ b_hh,
                       const float* __restrict__ hidden)
{
    const int i = blockIdx.x * 256 + threadIdx.x;
    const int ng = BATCH * 4 * HID;
    if (i < ng) {
        const int r = i & (4 * HID - 1);
        gates[i] = b_ih[r] + b_hh[r];
    } else {
        const int j = i - ng;
        if (j < BATCH * HID) hid_bf[j] = f2bu(hidden[j]);
    }
}

// ---------------------------------------------------------------------------
// Fused attention: single pass over encoder_states (512 MB), ~HBM roofline.
// relu(energy) >= 0 and small => exp without max-subtraction is safe.
// ---------------------------------------------------------------------------
__global__ __launch_bounds__(256, 4) void attn_k(
    const float* __restrict__ enc, const float* __restrict__ hidden,
    const float* __restrict__ W_e, const float* __restrict__ b_e,
    float* __restrict__ ctxPartial, float* __restrict__ lPartial)
{
    const int blk  = blockIdx.x;
    const int b    = blk >> 3;
    const int chnk = blk & 7;
    const int t    = threadIdx.x;
    const int wave = t >> 6;
    const int lane = t & 63;

    __shared__ float red[4];
    __shared__ float l_sh[4];
    __shared__ float ctx_sh[4][2048];

    float4 hv = *(const float4*)&hidden[(size_t)b * HID + t * 4];
    float4 wv = *(const float4*)&W_e[t * 4];
    float hl = hv.x * wv.x + hv.y * wv.y + hv.z * wv.z + hv.w * wv.w;
    #pragma unroll
    for (int off = 32; off > 0; off >>= 1) hl += __shfl_down(hl, off, 64);
    if (lane == 0) red[wave] = hl;
    __syncthreads();
    const float hdot = red[0] + red[1] + red[2] + red[3] + b_e[0];

    float4 w[8];
    #pragma unroll
    for (int j = 0; j < 8; j++)
        w[j] = *(const float4*)&W_e[HID + j * 256 + lane * 4];

    float4 c[8];
    #pragma unroll
    for (int j = 0; j < 8; j++) c[j] = make_float4(0.f, 0.f, 0.f, 0.f);
    float lsum = 0.f;

    #pragma unroll 1
    for (int i = 0; i < 16; i++) {
        const int s = chnk * 64 + wave + i * 4;
        const float* p = enc + ((size_t)s * BATCH + b) * 2048;
        float4 e[8];
        #pragma unroll
        for (int j = 0; j < 8; j++)
            e[j] = *(const float4*)&p[j * 256 + lane * 4];
        float d = 0.f;
        #pragma unroll
        for (int j = 0; j < 8; j++)
            d += e[j].x * w[j].x + e[j].y * w[j].y + e[j].z * w[j].z + e[j].w * w[j].w;
        #pragma unroll
        for (int off = 32; off > 0; off >>= 1) d += __shfl_xor(d, off, 64);
        float energy = d + hdot;
        energy = energy > 0.f ? energy : 0.f;
        const float pr = __expf(energy);
        lsum += pr;
        #pragma unroll
        for (int j = 0; j < 8; j++) {
            c[j].x += pr * e[j].x; c[j].y += pr * e[j].y;
            c[j].z += pr * e[j].z; c[j].w += pr * e[j].w;
        }
    }

    #pragma unroll
    for (int j = 0; j < 8; j++)
        *(float4*)&ctx_sh[wave][j * 256 + lane * 4] = c[j];
    if (lane == 0) l_sh[wave] = lsum;
    __syncthreads();

    float* outp = ctxPartial + (size_t)blk * 2048;
    #pragma unroll
    for (int j = 0; j < 8; j++) {
        const int idx = j * 256 + t;
        outp[idx] = ctx_sh[0][idx] + ctx_sh[1][idx] + ctx_sh[2][idx] + ctx_sh[3][idx];
    }
    if (t == 0) lPartial[blk] = l_sh[0] + l_sh[1] + l_sh[2] + l_sh[3];
}

// ---------------------------------------------------------------------------
// Combine partials -> normalized context (bf16) + embedding gather (bf16).
// rnn_bf[b, 0:2048] = context, rnn_bf[b, 2048:2560] = emb_table[x[b]]
// ---------------------------------------------------------------------------
__global__ void combine_k(const float* __restrict__ ctxPartial,
                          const float* __restrict__ lPartial,
                          const int* __restrict__ x,
                          const float* __restrict__ emb_table,
                          unsigned short* __restrict__ rnn_bf)
{
    const int b = blockIdx.x;
    const int t = threadIdx.x;
    float L = 0.f;
    #pragma unroll
    for (int cN = 0; cN < SPLIT; cN++) L += lPartial[b * SPLIT + cN];
    const float inv = 1.f / L;
    unsigned short* out = rnn_bf + (size_t)b * 2560;
    #pragma unroll
    for (int j = 0; j < 8; j++) {
        const int h = j * 256 + t;
        float v = 0.f;
        #pragma unroll
        for (int cN = 0; cN < SPLIT; cN++)
            v += ctxPartial[((size_t)(b * SPLIT + cN)) * 2048 + h];
        out[h] = f2bu(v * inv);
    }
    const int tok = x[b];
    for (int e2 = t; e2 < EMB; e2 += 256)
        out[2048 + e2] = f2bu(emb_table[(size_t)tok * EMB + e2]);
}

// ---------------------------------------------------------------------------
// gates += X_bf @ W^T via MFMA, fp32 W converted to bf16 in-registers.
// Grid: (64 n-blocks, 7 k-chunks). Chunks 0..4: rnn_bf/W_ih (k=2560 in 512s);
// chunks 5..6: hid_bf/W_hh (k=1024 in 512s). Atomic fp32 epilogue.
// Wave n-tile = 16 cols; 8 m-tiles cover all 128 batch rows.
// ---------------------------------------------------------------------------
__global__ __launch_bounds__(256) void gates_mfma_k(
    float* __restrict__ gates,
    const unsigned short* __restrict__ rnn_bf, const unsigned short* __restrict__ hid_bf,
    const float* __restrict__ W_ih, const float* __restrict__ W_hh)
{
    const int chunk = blockIdx.y;
    const unsigned short* X; const float* W; int Kx, Kw;
    if (chunk < 5) { X = rnn_bf + chunk * 512; W = W_ih + chunk * 512; Kx = 2560; Kw = 2560; }
    else           { X = hid_bf + (chunk - 5) * 512; W = W_hh + (chunk - 5) * 512; Kx = 1024; Kw = 1024; }

    const int t    = threadIdx.x;
    const int wave = t >> 6;
    const int lane = t & 63;
    const int ln   = lane & 15;
    const int q    = lane >> 4;
    const int n0   = (blockIdx.x * 4 + wave) * 16;

    f32x4 acc[8];
    #pragma unroll
    for (int mt = 0; mt < 8; mt++) acc[mt] = (f32x4){0.f, 0.f, 0.f, 0.f};

    const float* wrow = W + (size_t)(n0 + ln) * Kw;

    #pragma unroll 2
    for (int kk = 0; kk < 512; kk += 32) {
        const int k = kk + q * 8;
        float4 b0 = *(const float4*)&wrow[k];
        float4 b1 = *(const float4*)&wrow[k + 4];
        bf16x8 bf = cvt_bf8(b0, b1);
        #pragma unroll
        for (int mt = 0; mt < 8; mt++) {
            bf16x8 af = load_bf8(&X[(size_t)(mt * 16 + ln) * Kx + k]);
            acc[mt] = __builtin_amdgcn_mfma_f32_16x16x32_bf16(af, bf, acc[mt], 0, 0, 0);
        }
    }

    #pragma unroll
    for (int mt = 0; mt < 8; mt++) {
        #pragma unroll
        for (int r = 0; r < 4; r++) {
            const int m = mt * 16 + q * 4 + r;
            atomicAdd(&gates[(size_t)m * (4 * HID) + n0 + ln], acc[mt][r]);
        }
    }
}

// ---------------------------------------------------------------------------
// LSTM pointwise; also emits h_bf (bf16) as A-operand for the FC GEMM.
// ---------------------------------------------------------------------------
__global__ void lstm_k(const float* __restrict__ gates, const float* __restrict__ cell,
                       float* __restrict__ h_out, float* __restrict__ c_out,
                       unsigned short* __restrict__ h_bf)
{
    const int idx = blockIdx.x * 256 + threadIdx.x;
    const int b = idx >> 10;
    const int h = idx & 1023;
    const float* g = gates + (size_t)b * (4 * HID);
    const float ig = sigmoidf_(g[h]);
    const float fg = sigmoidf_(g[HID + h]);
    const float gg = tanhf(g[2 * HID + h]);
    const float og = sigmoidf_(g[3 * HID + h]);
    const float cn = fg * cell[idx] + ig * gg;
    const float hn = og * tanhf(cn);
    c_out[idx] = cn;
    h_out[idx] = hn;
    h_bf[idx] = f2bu(hn);
}

// ---------------------------------------------------------------------------
// pred = h_bf @ W_fc^T + b_fc via MFMA (fp32 W -> bf16 in-registers).
// 500 blocks x 4 waves, wave = one 16-col n-tile, full K=1024, no atomics.
// ---------------------------------------------------------------------------
__global__ __launch_bounds__(256) void fc_mfma_k(
    float* __restrict__ pred, const unsigned short* __restrict__ h_bf,
    const float* __restrict__ W_fc, const float* __restrict__ b_fc)
{
    const int t    = threadIdx.x;
    const int wave = t >> 6;
    const int lane = t & 63;
    const int ln   = lane & 15;
    const int q    = lane >> 4;
    const int n0   = (blockIdx.x * 4 + wave) * 16;

    f32x4 acc[8];
    #pragma unroll
    for (int mt = 0; mt < 8; mt++) acc[mt] = (f32x4){0.f, 0.f, 0.f, 0.f};

    const float* wrow = W_fc + (size_t)(n0 + ln) * HID;

    #pragma unroll 2
    for (int kk = 0; kk < HID; kk += 32) {
        const int k = kk + q * 8;
        float4 b0 = *(const float4*)&wrow[k];
        float4 b1 = *(const float4*)&wrow[k + 4];
        bf16x8 bf = cvt_bf8(b0, b1);
        #pragma unroll
        for (int mt = 0; mt < 8; mt++) {
            bf16x8 af = load_bf8(&h_bf[(size_t)(mt * 16 + ln) * HID + k]);
            acc[mt] = __builtin_amdgcn_mfma_f32_16x16x32_bf16(af, bf, acc[mt], 0, 0, 0);
        }
    }

    const float bias = b_fc[n0 + ln];
    #pragma unroll
    for (int mt = 0; mt < 8; mt++) {
        #pragma unroll
        for (int r = 0; r < 4; r++) {
            const int m = mt * 16 + q * 4 + r;
            pred[(size_t)m * VOCAB + n0 + ln] = acc[mt][r] + bias;
        }
    }
}

// ---------------------------------------------------------------------------
extern "C" void kernel_launch(void* const* d_in, const int* in_sizes, int n_in,
                              void* d_out, int out_size, void* d_ws, size_t ws_size,
                              hipStream_t stream)
{
    const int*   x      = (const int*)  d_in[0];
    const float* enc    = (const float*)d_in[1];
    const float* hidden = (const float*)d_in[2];
    const float* cell   = (const float*)d_in[3];
    const float* emb    = (const float*)d_in[4];
    const float* W_e    = (const float*)d_in[5];
    const float* b_e    = (const float*)d_in[6];
    const float* W_ih   = (const float*)d_in[7];
    const float* W_hh   = (const float*)d_in[8];
    const float* b_ih   = (const float*)d_in[9];
    const float* b_hh   = (const float*)d_in[10];
    const float* W_fc   = (const float*)d_in[11];
    const float* b_fc   = (const float*)d_in[12];

    float* pred  = (float*)d_out;                       // [128, 32000]
    float* h_out = pred + (size_t)BATCH * VOCAB;        // [128, 1024]
    float* c_out = h_out + BATCH * HID;                 // [128, 1024]

    float* ws         = (float*)d_ws;
    float* ctxPartial = ws;                                        // 2,097,152 f
    float* lPartial   = ctxPartial + (size_t)BATCH * SPLIT * 2048; // 1,024 f
    float* gates      = lPartial + BATCH * SPLIT;                  // 524,288 f
    unsigned short* rnn_bf = (unsigned short*)(gates + (size_t)BATCH * 4 * HID); // 128*2560
    unsigned short* hid_bf = rnn_bf + (size_t)BATCH * 2560;        // 128*1024
    unsigned short* h_bf   = hid_bf + (size_t)BATCH * HID;         // 128*1024

    // 1) bias-init gates accumulator + hidden->bf16
    init_k<<<2560, 256, 0, stream>>>(gates, hid_bf, b_ih, b_hh, hidden);
    // 2) fused attention (single pass over 512 MB encoder_states)
    attn_k<<<BATCH * SPLIT, 256, 0, stream>>>(enc, hidden, W_e, b_e, ctxPartial, lPartial);
    // 3) normalize + embedding gather -> rnn_bf (bf16)
    combine_k<<<BATCH, 256, 0, stream>>>(ctxPartial, lPartial, x, emb, rnn_bf);
    // 4) gates += [rnn,hid] @ [W_ih,W_hh]^T  (MFMA, 7-way k-split, 448 blocks)
    gates_mfma_k<<<dim3(64, 7), 256, 0, stream>>>(gates, rnn_bf, hid_bf, W_ih, W_hh);
    // 5) LSTM pointwise -> h_new, c_new, h_bf
    lstm_k<<<(BATCH * HID) / 256, 256, 0, stream>>>(gates, cell, h_out, c_out, h_bf);
    // 6) pred = h_bf @ W_fc^T + b_fc  (MFMA, 500 blocks, no atomics)
    fc_mfma_k<<<VOCAB / 64, 256, 0, stream>>>(pred, h_bf, W_fc, b_fc);
}